// Round 2
// baseline (343.283 us; speedup 1.0000x reference)
//
#include <hip/hip_runtime.h>
#include <hip/hip_bf16.h>
#include <math.h>

// ---------------------------------------------------------------------------
// BNAF flow (DIM=64, HID=32, B=1024).  R17: exploit block-lower-triangular
// weight masks everywhere: gemm1 skips dead K-chunks (53% live), act_grad
// reads only live partials (avg 2.5/4) and skips zero output rows, tail
// reads only live out2p partials (~half), gemm0 clamps its c-loop (~56%
// live avg), prep clamps W1/W2 row loads + W1 writes to the live prefix
// and uses float4 loads with 4 rows/block. 13 dispatches.
// ---------------------------------------------------------------------------

#define DIMN 64
#define BATCH 1024
#define HIDF 2048   // DIM*HID
#define SPLITK 4
#define NT2 32      // out2 partial count (= HIDF/64 n-tiles)

typedef __attribute__((ext_vector_type(8))) short short8;
typedef __attribute__((ext_vector_type(4))) short short4v;
typedef __attribute__((ext_vector_type(4))) float floatx4;

__device__ __forceinline__ float softplusf_(float t) {
    return fmaxf(t, 0.f) + log1pf(__expf(-fabsf(t)));
}

__device__ __forceinline__ float bf2f(short v) {
    union { unsigned u; float f; } x;
    x.u = ((unsigned)(unsigned short)v) << 16;
    return x.f;
}

__device__ __forceinline__ void gl_lds16(const void* g, void* l) {
    __builtin_amdgcn_global_load_lds(
        (const __attribute__((address_space(1))) unsigned int*)g,
        (__attribute__((address_space(3))) unsigned int*)l, 16, 0, 0);
}

// tanh + sech^2 from ONE exp:  t = e^{-2|p|}; tanh = sign(p)(1-t)/(1+t);
// sech^2 = 4t/(1+t)^2.
__device__ __forceinline__ void tanh_sech2_(float p, float& th, float& s2) {
    float t = __expf(-2.f * fabsf(p));
    float opt = 1.f + t;
    float inv = 1.f / opt;
    th = copysignf((1.f - t) * inv, p);
    s2 = 4.f * t * inv * inv;
}

// ---------------------------------------------------------------------------
// prep workers.  W row r of an (out_f x in_f) masked weight:
//   w = exp(W)*md + W*mo  (block-lower-triangular: row-block d live cols < c1)
//   wn = exp(dw)*w/sqrt(wsn); eg[r*ib+k] = exp(dw + W[r][c0+k] - 0.5 log wsn)
// ---------------------------------------------------------------------------

// W0: (2048 x 64), ob=32, ib=1. Transposed f32 output wn0T[c][r].
__device__ __forceinline__ void prep_row0(
    const float* __restrict__ W, const float* __restrict__ dw,
    float* __restrict__ wn0T, float* __restrict__ eg0, int r, int lane)
{
    int d = r >> 5;                 // c0 = d, c1 = d+1
    const float* Wr = W + (size_t)r * 64;
    float wraw = Wr[lane];
    float wv = (lane < d) ? wraw : ((lane == d) ? __expf(wraw) : 0.f);
    float ss = wv * wv;
    for (int off = 32; off > 0; off >>= 1) ss += __shfl_xor(ss, off, 64);
    float dwr = dw[r];
    float scale = __expf(dwr) / sqrtf(ss);
    wn0T[(size_t)lane * HIDF + r] = scale * wv;
    if (lane == 0) eg0[r] = __expf(dwr - 0.5f * __logf(ss) + Wr[d]);
}

// W1/W2: (out_f x 2048), ib=32. bf16 row-major output. Loads clamped to ni
// 256-col chunks (covers live prefix c1), writes clamped to nw chunks
// (must cover everything the consumer GEMM stages).
__device__ __forceinline__ void prep_row_wide(
    const float* __restrict__ W, const float* __restrict__ dw,
    __hip_bfloat16* __restrict__ wn, float* __restrict__ eg,
    int r, int lane, int d, int ni, int nw)
{
    int c0 = d * 32, c1 = c0 + 32;
    const float* Wr = W + (size_t)r * 2048;
    float4 vv[8];
    float ss = 0.f;
#pragma unroll
    for (int i = 0; i < 8; ++i) {
        vv[i] = (float4){0.f, 0.f, 0.f, 0.f};
        if (i < ni) {
            int cb = i * 256 + lane * 4;
            float4 v = *(const float4*)&Wr[cb];
            float w0 = (cb + 0 < c0) ? v.x : ((cb + 0 < c1) ? __expf(v.x) : 0.f);
            float w1 = (cb + 1 < c0) ? v.y : ((cb + 1 < c1) ? __expf(v.y) : 0.f);
            float w2 = (cb + 2 < c0) ? v.z : ((cb + 2 < c1) ? __expf(v.z) : 0.f);
            float w3 = (cb + 3 < c0) ? v.w : ((cb + 3 < c1) ? __expf(v.w) : 0.f);
            vv[i] = (float4){w0, w1, w2, w3};
            ss += w0 * w0 + w1 * w1 + w2 * w2 + w3 * w3;
        }
    }
    for (int off = 32; off > 0; off >>= 1) ss += __shfl_xor(ss, off, 64);
    float dwr = dw[r];
    float scale = __expf(dwr) / sqrtf(ss);
    float logt = dwr - 0.5f * __logf(ss);
#pragma unroll
    for (int i = 0; i < 8; ++i) {
        if (i < nw) {
            int cb = i * 256 + lane * 4;
            __hip_bfloat16 b0 = __float2bfloat16(scale * vv[i].x);
            __hip_bfloat16 b1 = __float2bfloat16(scale * vv[i].y);
            __hip_bfloat16 b2 = __float2bfloat16(scale * vv[i].z);
            __hip_bfloat16 b3 = __float2bfloat16(scale * vv[i].w);
            short4v pk = { *(short*)&b0, *(short*)&b1, *(short*)&b2, *(short*)&b3 };
            *(short4v*)((short*)wn + (size_t)r * 2048 + cb) = pk;
        }
    }
    if (lane < 32) eg[(size_t)r * 32 + lane] = __expf(logt + Wr[c0 + lane]);
}

struct PrepIn { const float *W0, *dw0, *W1, *dw1, *W2, *dw2; };

// 4 rows/block (one per wave): grid 3 * (512 + 512 + 16) = 3120, 256 thr.
__global__ __launch_bounds__(256) void prep_mega(
    PrepIn p0, PrepIn p1, PrepIn p2,
    float* __restrict__ wn0T_all, float* __restrict__ eg0_all,
    __hip_bfloat16* __restrict__ wn1_all, float* __restrict__ e1_all,
    __hip_bfloat16* __restrict__ wn2b_all, float* __restrict__ e2_all)
{
    int blk = blockIdx.x;
    int wave = threadIdx.x >> 6;
    int lane = threadIdx.x & 63;
    int f = blk / 1040;
    int rem = blk - f * 1040;
    PrepIn P = (f == 0) ? p0 : ((f == 1) ? p1 : p2);

    float* wn0T = wn0T_all + (size_t)f * DIMN * HIDF;
    float* eg0  = eg0_all  + (size_t)f * HIDF;
    __hip_bfloat16* wn1 = wn1_all + (size_t)f * HIDF * HIDF;
    float* e1   = e1_all   + (size_t)f * HIDF * 32;
    __hip_bfloat16* wn2b = wn2b_all + (size_t)f * DIMN * HIDF;
    float* e2   = e2_all   + (size_t)f * DIMN * 32;

    if (rem < 512) {
        int r = rem * 4 + wave;
        prep_row0(P.W0, P.dw0, wn0T, eg0, r, lane);
    } else if (rem < 1024) {
        int r = (rem - 512) * 4 + wave;
        // d = r/32; live c1 = (d+1)*32 -> ni = r/256+1. gemm1 stages
        // k < (r/128+1)*128 -> nw = r/256+1 (same).
        prep_row_wide(P.W1, P.dw1, wn1, e1, r, lane, r >> 5, (r >> 8) + 1, (r >> 8) + 1);
    } else {
        int r = (rem - 1024) * 4 + wave;
        // d = r; live c1 = (r+1)*32 -> ni = r/8+1. gemm2 stages all cols -> nw=8.
        prep_row_wide(P.W2, P.dw2, wn2b, e2, r, lane, r, (r >> 3) + 1, 8);
    }
}

// ---------------------------------------------------------------------------
// gemm0_act: pre0 = x @ wn0T + b0 ; h0 = tanh(pre0) bf16;
// g0e[b,n] = eg0[n] * sech^2(pre0)  (bf16). grid (8, 64), 256 threads.
// Triangular: wn0T[c][n]=0 for c > n/32 -> clamp c-loop to 2*bx+2 chunks.
// ---------------------------------------------------------------------------
__global__ __launch_bounds__(256) void gemm0_act(
    const float* __restrict__ xin, const float* __restrict__ wn0T,
    const float* __restrict__ bias, const float* __restrict__ eg0,
    __hip_bfloat16* __restrict__ h0, __hip_bfloat16* __restrict__ g0e)
{
    __shared__ float xs[16][DIMN];
    int b0 = blockIdx.y * 16;
    {
        const float4* src = (const float4*)(xin + (size_t)b0 * DIMN);
        ((float4*)xs)[threadIdx.x] = src[threadIdx.x];
    }
    __syncthreads();
    int n = blockIdx.x * 256 + threadIdx.x;

    float acc[16];
#pragma unroll
    for (int j = 0; j < 16; ++j) acc[j] = 0.f;

    int c4max = 2 * blockIdx.x + 2;   // live c < (n_max/32)+1 <= 4*c4max
#pragma unroll 2
    for (int c4 = 0; c4 < c4max; ++c4) {
        int c = c4 * 4;
        float w0 = wn0T[(size_t)(c + 0) * HIDF + n];
        float w1 = wn0T[(size_t)(c + 1) * HIDF + n];
        float w2 = wn0T[(size_t)(c + 2) * HIDF + n];
        float w3 = wn0T[(size_t)(c + 3) * HIDF + n];
#pragma unroll
        for (int j = 0; j < 16; ++j) {
            float4 x4 = *(const float4*)&xs[j][c];
            acc[j] = fmaf(x4.x, w0, acc[j]);
            acc[j] = fmaf(x4.y, w1, acc[j]);
            acc[j] = fmaf(x4.z, w2, acc[j]);
            acc[j] = fmaf(x4.w, w3, acc[j]);
        }
    }
    float bv = bias[n], egv = eg0[n];
#pragma unroll
    for (int j = 0; j < 16; ++j) {
        float p = acc[j] + bv;
        float th, s2;
        tanh_sech2_(p, th, s2);
        size_t idx = (size_t)(b0 + j) * HIDF + n;
        h0[idx] = __float2bfloat16(th);
        g0e[idx] = __float2bfloat16(egv * s2);
    }
}

// ---------------------------------------------------------------------------
// gemm1_part: partial[kc][m][n] = sum_{k in chunk kc} h0[m,k]*wn1[n,k] (bf16)
// 128x128 tile, 4 waves each owning a 64x64 quadrant (4x4 16x16 frags),
// BK=64, XOR chunk swizzle, global_load_lds 16B staging.
// Triangular: n-tile jn only needs k < (jn+1)*128 -> clamp kend, dead
// (jn,kz) blocks exit immediately (40 of 64 live).
// ---------------------------------------------------------------------------
#define G1BK 64
__global__ __launch_bounds__(256) void gemm1_part(
    const __hip_bfloat16* __restrict__ A, const __hip_bfloat16* __restrict__ B,
    __hip_bfloat16* __restrict__ part)
{
    const int K = HIDF, N = HIDF;
    int jn = blockIdx.x;
    int kbase = blockIdx.z * (K / SPLITK);
    int kend = (jn + 1) * 128 - kbase;          // live K within this chunk
    if (kend <= 0) return;
    if (kend > K / SPLITK) kend = K / SPLITK;

    __shared__ short As[128 * 64];   // 16 KB [128 m][64 k] swizzled
    __shared__ short Bs[128 * 64];   // 16 KB [128 n][64 k] swizzled
    int tid = threadIdx.x;
    int lane = tid & 63;
    int wave = tid >> 6;
    int n0 = jn * 128;
    int m0 = blockIdx.y * 128;
    int wr = wave >> 1;   // m half (64 rows)
    int wc = wave & 1;    // n half (64 cols)

    int rf = lane & 15;
    int q = lane >> 4;    // 0..3

    const char* agp[4];
    const char* bgp[4];
    char* alds[4];
    char* blds[4];
#pragma unroll
    for (int s = 0; s < 4; ++s) {
        int c = tid + s * 256;
        int row = c >> 3;
        int kc = (c & 7) ^ (row & 7);
        agp[s] = (const char*)A + ((size_t)(m0 + row) * K + kbase) * 2 + kc * 16;
        bgp[s] = (const char*)B + ((size_t)(n0 + row) * K + kbase) * 2 + kc * 16;
        alds[s] = (char*)As + c * 16;
        blds[s] = (char*)Bs + c * 16;
    }

    floatx4 acc[4][4];
#pragma unroll
    for (int i = 0; i < 4; ++i)
#pragma unroll
        for (int j = 0; j < 4; ++j) acc[i][j] = (floatx4){0.f, 0.f, 0.f, 0.f};

    int rowA0 = wr * 64 + rf;
    int rowB0 = wc * 64 + rf;

    for (int k0 = 0; k0 < kend; k0 += G1BK) {
        size_t kb = (size_t)k0 * 2;
        __syncthreads();
#pragma unroll
        for (int s = 0; s < 4; ++s) {
            gl_lds16(agp[s] + kb, alds[s]);
            gl_lds16(bgp[s] + kb, blds[s]);
        }
        __syncthreads();

#pragma unroll
        for (int s = 0; s < 2; ++s) {
            short8 af[4], bfv[4];
#pragma unroll
            for (int i = 0; i < 4; ++i) {
                int row = rowA0 + i * 16;
                af[i] = *(const short8*)&As[row * 64 + (((s * 4 + q) ^ (row & 7)) * 8)];
            }
#pragma unroll
            for (int j = 0; j < 4; ++j) {
                int row = rowB0 + j * 16;
                bfv[j] = *(const short8*)&Bs[row * 64 + (((s * 4 + q) ^ (row & 7)) * 8)];
            }
#pragma unroll
            for (int i = 0; i < 4; ++i)
#pragma unroll
                for (int j = 0; j < 4; ++j)
                    acc[i][j] = __builtin_amdgcn_mfma_f32_16x16x32_bf16(af[i], bfv[j], acc[i][j], 0, 0, 0);
        }
    }

    __hip_bfloat16* pk = part + (size_t)blockIdx.z * BATCH * HIDF;
    int col = lane & 15;
    int rq = (lane >> 4) * 4;
#pragma unroll
    for (int i = 0; i < 4; ++i) {
#pragma unroll
        for (int j = 0; j < 4; ++j) {
            int n = n0 + wc * 64 + j * 16 + col;
#pragma unroll
            for (int r = 0; r < 4; ++r) {
                int m = m0 + wr * 64 + i * 16 + rq + r;
                pk[(size_t)m * N + n] = __float2bfloat16(acc[i][j][r]);
            }
        }
    }
}

// ---------------------------------------------------------------------------
// act_grad_gemm2: per 64b x 64n tile:
//  Phase A: pre1 = sum_{p<np} part[p]+bias; h1 (bf16) -> LDS;
//           grad1e = sech^2(pre1) * sum_k E1[n,k]*g0e[b,(n&~31)+k]  -> global
//  Phase B: out2p[ntile][b][d] = h1_tile @ wn2b[d, n0:n0+64]^T, but rows
//           d < 2*bx are identically zero AND never read by tail -> skip
//           MFMA + write for j < jact0 = bx>>3.
// np = bx>>3 + 1 live partials (matches gemm1's live kz set exactly).
// ---------------------------------------------------------------------------
__global__ __launch_bounds__(256) void act_grad_gemm2(
    const __hip_bfloat16* __restrict__ part, const float* __restrict__ bias,
    const float* __restrict__ e1, const __hip_bfloat16* __restrict__ g0e,
    const __hip_bfloat16* __restrict__ wn2b,
    __hip_bfloat16* __restrict__ grad1e, float* __restrict__ out2p)
{
    __shared__ char smem[17408 + 8704 + 8192];
    float* g0s = (float*)smem;                          // 64 x 68 floats
    short* h1s = (short*)(smem + 17408);                // 64 x 68 shorts (pad)
    short* Bs2 = (short*)(smem + 17408 + 8704);         // 64 x 64 swizzled

    int tid = threadIdx.x;
    int lane = tid & 63;
    int wave = tid >> 6;
    int bx = blockIdx.x;
    int n0 = bx * 64;
    int b0 = blockIdx.y * 64;
    int np = (bx >> 3) + 1;      // live partials
    int jact0 = bx >> 3;         // first live output d-frag (d >= 2*bx)

    // early async stage of wn2b k-slice [64 d][n0..n0+64] (XOR swizzle)
    {
        int c0c = tid, c1c = tid + 256;
        int r0 = c0c >> 3, k0c = (c0c & 7) ^ (r0 & 7);
        int r1 = c1c >> 3, k1c = (c1c & 7) ^ (r1 & 7);
        gl_lds16((const char*)wn2b + ((size_t)r0 * HIDF + n0) * 2 + k0c * 16,
                 (char*)Bs2 + c0c * 16);
        gl_lds16((const char*)wn2b + ((size_t)r1 * HIDF + n0) * 2 + k1c * 16,
                 (char*)Bs2 + c1c * 16);
    }

    // stage g0e tile [64 b][64 c] bf16 -> f32 LDS (pad 68)
    for (int s = tid; s < 512; s += 256) {
        int row = s >> 3, c8 = s & 7;
        short8 v = *(const short8*)((const short*)g0e +
                                    (size_t)(b0 + row) * HIDF + n0 + c8 * 8);
        float4 lo = { bf2f(v[0]), bf2f(v[1]), bf2f(v[2]), bf2f(v[3]) };
        float4 hi = { bf2f(v[4]), bf2f(v[5]), bf2f(v[6]), bf2f(v[7]) };
        *(float4*)&g0s[row * 68 + c8 * 8] = lo;
        *(float4*)&g0s[row * 68 + c8 * 8 + 4] = hi;
    }

    int g = tid >> 6;        // b-group 0..3
    int nl = tid & 63;       // local n
    int n = n0 + nl;

    // E1 row for this n into registers (32 floats)
    float4 er[8];
    const float4* e1r = (const float4*)(e1 + (size_t)n * 32);
#pragma unroll
    for (int qq = 0; qq < 8; ++qq) er[qq] = e1r[qq];

    float bv = bias[n];
    int kb2 = nl & 32;
    const __hip_bfloat16* pp0 = part;
    const __hip_bfloat16* pp1 = part + (size_t)1 * BATCH * HIDF;
    const __hip_bfloat16* pp2 = part + (size_t)2 * BATCH * HIDF;
    const __hip_bfloat16* pp3 = part + (size_t)3 * BATCH * HIDF;

    __syncthreads();

    // Phase A
#pragma unroll
    for (int t = 0; t < 16; ++t) {
        int bl = g * 16 + t;
        int b = b0 + bl;
        size_t idx = (size_t)b * HIDF + n;
        float pre = bv + __bfloat162float(pp0[idx]);
        if (np > 1) pre += __bfloat162float(pp1[idx]);
        if (np > 2) pre += __bfloat162float(pp2[idx]);
        if (np > 3) pre += __bfloat162float(pp3[idx]);
        float th, s2;
        tanh_sech2_(pre, th, s2);
        const float* g0row = &g0s[bl * 68 + kb2];
        float dot = 0.f;
#pragma unroll
        for (int qq = 0; qq < 8; ++qq) {
            float4 gv = *(const float4*)&g0row[qq * 4];
            dot = fmaf(gv.x, er[qq].x, dot);
            dot = fmaf(gv.y, er[qq].y, dot);
            dot = fmaf(gv.z, er[qq].z, dot);
            dot = fmaf(gv.w, er[qq].w, dot);
        }
        __hip_bfloat16 thb = __float2bfloat16(th);
        h1s[bl * 68 + nl] = *(const short*)&thb;
        grad1e[idx] = __float2bfloat16(dot * s2);
    }
    __syncthreads();

    // Phase B: 64b x 64d GEMM over K=64 (the nl slice), live j >= jact0
    int rf = lane & 15;
    int q = lane >> 4;
    floatx4 acc2[4];
#pragma unroll
    for (int j = 0; j < 4; ++j) acc2[j] = (floatx4){0.f, 0.f, 0.f, 0.f};

#pragma unroll
    for (int s = 0; s < 2; ++s) {
        int rowa = wave * 16 + rf;
        short8 af = *(const short8*)&h1s[rowa * 68 + s * 32 + q * 8];
#pragma unroll
        for (int j = 0; j < 4; ++j) {
            if (j >= jact0) {
                int rowb = j * 16 + rf;
                int cp = (s * 4 + q) ^ (rowb & 7);
                short8 bfv = *(const short8*)&Bs2[rowb * 64 + cp * 8];
                acc2[j] = __builtin_amdgcn_mfma_f32_16x16x32_bf16(af, bfv, acc2[j], 0, 0, 0);
            }
        }
    }

    float* outk = out2p + (size_t)bx * BATCH * DIMN;
    int col = lane & 15;
    int rq = (lane >> 4) * 4;
#pragma unroll
    for (int j = 0; j < 4; ++j) {
        if (j >= jact0) {
#pragma unroll
            for (int r = 0; r < 4; ++r) {
                int m = b0 + wave * 16 + rq + r;
                outk[(size_t)m * DIMN + j * 16 + col] = acc2[j][r];
            }
        }
    }
}

// ---------------------------------------------------------------------------
// tail_trans: one wave per batch row. out2p partial p is zero at d unless
// p <= d/2 -> exec-masked loop reads only live partials (~half traffic).
// ---------------------------------------------------------------------------
__global__ __launch_bounds__(256) void tail_trans(
    const float* __restrict__ out2p, const float* __restrict__ b2,
    const float* __restrict__ e2, const __hip_bfloat16* __restrict__ grad1e,
    const float* __restrict__ x_cur, const float* __restrict__ gate,
    float* __restrict__ x_next, float* __restrict__ ldj, int accum_ldj)
{
    int tid = threadIdx.x;
    int b = blockIdx.x * 4 + (tid >> 6);
    int n = tid & 63;

    float o = b2[n];
    int pmax = n >> 1;
    for (int p = 0; p <= pmax; ++p)
        o += out2p[(size_t)p * BATCH * DIMN + (size_t)b * DIMN + n];

    float gt = gate[0];
    float sg = 1.f / (1.f + __expf(-gt));
    float xo = sg * o + (1.f - sg) * x_cur[(size_t)b * DIMN + n];
    x_next[(size_t)b * DIMN + (63 - n)] = xo;

    const short8* gr = (const short8*)((const short*)grad1e + (size_t)b * HIDF + n * 32);
    const float4* gc = (const float4*)(e2 + n * 32);
    float s = 0.f;
#pragma unroll
    for (int q = 0; q < 4; ++q) {
        short8 a8 = gr[q];
        float4 c0 = gc[2 * q], c1 = gc[2 * q + 1];
        s = fmaf(bf2f(a8[0]), c0.x, s);
        s = fmaf(bf2f(a8[1]), c0.y, s);
        s = fmaf(bf2f(a8[2]), c0.z, s);
        s = fmaf(bf2f(a8[3]), c0.w, s);
        s = fmaf(bf2f(a8[4]), c1.x, s);
        s = fmaf(bf2f(a8[5]), c1.y, s);
        s = fmaf(bf2f(a8[6]), c1.z, s);
        s = fmaf(bf2f(a8[7]), c1.w, s);
    }
    float gF = __logf(fmaxf(s, 1e-45f));
    float contrib = softplusf_(gF + gt) - softplusf_(gt);
    for (int off = 32; off > 0; off >>= 1) contrib += __shfl_xor(contrib, off, 64);
    if (n == 0) ldj[b] = accum_ldj ? (ldj[b] + contrib) : contrib;
}

// ---------------------------------------------------------------------------
// tail_final (flow 2): out[b] = ldj[b] + sum_n(gF - 0.5*o^2 - 0.5*log(2pi))
// ---------------------------------------------------------------------------
__global__ __launch_bounds__(256) void tail_final(
    const float* __restrict__ out2p, const float* __restrict__ b2,
    const float* __restrict__ e2, const __hip_bfloat16* __restrict__ grad1e,
    const float* __restrict__ ldj, float* __restrict__ out)
{
    int tid = threadIdx.x;
    int b = blockIdx.x * 4 + (tid >> 6);
    int n = tid & 63;

    float o = b2[n];
    int pmax = n >> 1;
    for (int p = 0; p <= pmax; ++p)
        o += out2p[(size_t)p * BATCH * DIMN + (size_t)b * DIMN + n];

    const short8* gr = (const short8*)((const short*)grad1e + (size_t)b * HIDF + n * 32);
    const float4* gc = (const float4*)(e2 + n * 32);
    float s = 0.f;
#pragma unroll
    for (int q = 0; q < 4; ++q) {
        short8 a8 = gr[q];
        float4 c0 = gc[2 * q], c1 = gc[2 * q + 1];
        s = fmaf(bf2f(a8[0]), c0.x, s);
        s = fmaf(bf2f(a8[1]), c0.y, s);
        s = fmaf(bf2f(a8[2]), c0.z, s);
        s = fmaf(bf2f(a8[3]), c0.w, s);
        s = fmaf(bf2f(a8[4]), c1.x, s);
        s = fmaf(bf2f(a8[5]), c1.y, s);
        s = fmaf(bf2f(a8[6]), c1.z, s);
        s = fmaf(bf2f(a8[7]), c1.w, s);
    }
    float gF = __logf(fmaxf(s, 1e-45f));

    float contrib = gF - 0.5f * o * o - 0.91893853320467274f; // -0.5*log(2pi)
    for (int off = 32; off > 0; off >>= 1) contrib += __shfl_xor(contrib, off, 64);
    if (n == 0) out[b] = ldj[b] + contrib;
}

// ---------------------------------------------------------------------------
extern "C" void kernel_launch(void* const* d_in, const int* in_sizes, int n_in,
                              void* d_out, int out_size, void* d_ws, size_t ws_size,
                              hipStream_t stream)
{
    (void)in_sizes; (void)n_in; (void)out_size; (void)ws_size;

    const float* x = (const float*)d_in[0];
    const float* gates[2] = { (const float*)d_in[28], (const float*)d_in[29] };

    char* ws = (char*)d_ws;
    size_t ofs = 0;
    auto alloc = [&](size_t bytes) { char* p = ws + ofs; ofs += (bytes + 255) & ~(size_t)255; return p; };

    __hip_bfloat16* wn1_all  = (__hip_bfloat16*)alloc((size_t)3 * HIDF * HIDF * 2);  // 24 MB
    __hip_bfloat16* wn2b_all = (__hip_bfloat16*)alloc((size_t)3 * DIMN * HIDF * 2);
    float* wn0T_all = (float*)alloc((size_t)3 * DIMN * HIDF * 4);
    float* eg0_all  = (float*)alloc((size_t)3 * HIDF * 4);
    float* e1_all   = (float*)alloc((size_t)3 * HIDF * 32 * 4);
    float* e2_all   = (float*)alloc((size_t)3 * DIMN * 32 * 4);
    __hip_bfloat16* h0   = (__hip_bfloat16*)alloc((size_t)BATCH * HIDF * 2);
    __hip_bfloat16* part = (__hip_bfloat16*)alloc((size_t)SPLITK * BATCH * HIDF * 2); // 16 MB
    __hip_bfloat16* g0e    = (__hip_bfloat16*)alloc((size_t)BATCH * HIDF * 2);
    __hip_bfloat16* grad1e = (__hip_bfloat16*)alloc((size_t)BATCH * HIDF * 2);
    float* out2p  = (float*)alloc((size_t)NT2 * BATCH * DIMN * 4);                    // 8 MB
    float* x1     = (float*)alloc((size_t)BATCH * DIMN * 4);
    float* x2     = (float*)alloc((size_t)BATCH * DIMN * 4);
    float* ldj    = (float*)alloc(BATCH * 4);
    float* outp   = (float*)d_out;

    auto W = [&](int f, int i) { return (const float*)d_in[1 + f * 9 + i]; };

    PrepIn p0 = { W(0,0), W(0,1), W(0,3), W(0,4), W(0,6), W(0,7) };
    PrepIn p1 = { W(1,0), W(1,1), W(1,3), W(1,4), W(1,6), W(1,7) };
    PrepIn p2 = { W(2,0), W(2,1), W(2,3), W(2,4), W(2,6), W(2,7) };

    prep_mega<<<dim3(3 * 1040), dim3(256), 0, stream>>>(
        p0, p1, p2, wn0T_all, eg0_all, wn1_all, e1_all, wn2b_all, e2_all);

    gemm0_act<<<dim3(8, BATCH / 16), dim3(256), 0, stream>>>(
        x, wn0T_all, W(0,2), eg0_all, h0, g0e);

    const float* xcur = x;
    float* xnexts[2] = { x1, x2 };

    for (int f = 0; f < 3; ++f) {
        size_t fo1 = (size_t)f * HIDF * HIDF;
        size_t fo2 = (size_t)f * DIMN * HIDF;

        gemm1_part<<<dim3(HIDF / 128, BATCH / 128, SPLITK), dim3(256), 0, stream>>>(
            h0, wn1_all + fo1, part);

        act_grad_gemm2<<<dim3(HIDF / 64, BATCH / 64), dim3(256), 0, stream>>>(
            part, W(f,5), e1_all + (size_t)f * HIDF * 32, g0e,
            wn2b_all + fo2, grad1e, out2p);

        if (f < 2) {
            tail_trans<<<dim3(BATCH / 4), dim3(256), 0, stream>>>(
                out2p, W(f,8), e2_all + (size_t)f * DIMN * 32, grad1e,
                xcur, gates[f], xnexts[f], ldj, f);

            gemm0_act<<<dim3(8, BATCH / 16), dim3(256), 0, stream>>>(
                xnexts[f], wn0T_all + (size_t)(f + 1) * DIMN * HIDF, W(f + 1, 2),
                eg0_all + (size_t)(f + 1) * HIDF, h0, g0e);

            xcur = xnexts[f];
        } else {
            tail_final<<<dim3(BATCH / 4), dim3(256), 0, stream>>>(
                out2p, W(2,8), e2_all + (size_t)2 * DIMN * 32, grad1e, ldj, outp);
        }
    }
}

// Round 3
// 331.023 us; speedup vs baseline: 1.0370x; 1.0370x over previous
//
#include <hip/hip_runtime.h>
#include <hip/hip_bf16.h>
#include <math.h>

// ---------------------------------------------------------------------------
// BNAF flow (DIM=64, HID=32, B=1024).  R18: revert to R16 structure (291us)
// except: gemm1 runs only the 40 live triangular (jn,kz) blocks via an
// LPT-sorted constant schedule (2176 of 4096 K-iters, longest-first for CU
// balance); act_grad reads only live partials (uniform branches) and skips
// provably-zero MFMA output frags while still writing the zeros so the
// fully-unrolled static tails stay valid. 13 dispatches.
// ---------------------------------------------------------------------------

#define DIMN 64
#define BATCH 1024
#define HIDF 2048   // DIM*HID
#define SPLITK 4
#define NT2 32      // out2 partial count (= HIDF/64 n-tiles)

typedef __attribute__((ext_vector_type(8))) short short8;
typedef __attribute__((ext_vector_type(4))) float floatx4;

__device__ __forceinline__ float softplusf_(float t) {
    return fmaxf(t, 0.f) + log1pf(__expf(-fabsf(t)));
}

__device__ __forceinline__ float bf2f(short v) {
    union { unsigned u; float f; } x;
    x.u = ((unsigned)(unsigned short)v) << 16;
    return x.f;
}

__device__ __forceinline__ void gl_lds16(const void* g, void* l) {
    __builtin_amdgcn_global_load_lds(
        (const __attribute__((address_space(1))) unsigned int*)g,
        (__attribute__((address_space(3))) unsigned int*)l, 16, 0, 0);
}

// tanh + sech^2 from ONE exp:  t = e^{-2|p|}; tanh = sign(p)(1-t)/(1+t);
// sech^2 = 4t/(1+t)^2.
__device__ __forceinline__ void tanh_sech2_(float p, float& th, float& s2) {
    float t = __expf(-2.f * fabsf(p));
    float opt = 1.f + t;
    float inv = 1.f / opt;
    th = copysignf((1.f - t) * inv, p);
    s2 = 4.f * t * inv * inv;
}

// ---------------------------------------------------------------------------
// prep row worker: one wave per output row r of W (out_f x INF).
//  wn = exp(dw)*w/sqrt(wsn); eg[r*ib+k] = exp(dw + W[r][c0+k] - 0.5 log wsn)
// ---------------------------------------------------------------------------
template<int INF>
__device__ __forceinline__ void prep_row(
    const float* __restrict__ W, const float* __restrict__ dw,
    void* __restrict__ wn_out, float* __restrict__ eg,
    int r, int lane, int out_f, int ob, int ib, int transpose, int bf16out)
{
    constexpr int NI = INF / 64;
    int d = r / ob;
    int c0 = d * ib;
    int c1 = c0 + ib;
    const float* Wr = W + (size_t)r * INF;

    float vv[NI];
    float ss = 0.f;
#pragma unroll
    for (int i = 0; i < NI; ++i) {
        int c = lane + i * 64;
        float wraw = Wr[c];
        float wv = (c < c0) ? wraw : ((c < c1) ? __expf(wraw) : 0.f);
        vv[i] = wv;
        ss += wv * wv;
    }
    for (int off = 32; off > 0; off >>= 1) ss += __shfl_xor(ss, off, 64);

    float dwr = dw[r];
    float scale = __expf(dwr) / sqrtf(ss);
    float logt = dwr - 0.5f * __logf(ss);

#pragma unroll
    for (int i = 0; i < NI; ++i) {
        int c = lane + i * 64;
        float val = scale * vv[i];
        if (bf16out) {
            ((__hip_bfloat16*)wn_out)[(size_t)r * INF + c] = __float2bfloat16(val);
        } else if (transpose) {
            ((float*)wn_out)[(size_t)c * out_f + r] = val;
        } else {
            ((float*)wn_out)[(size_t)r * INF + c] = val;
        }
    }
    if (lane < ib) eg[(size_t)r * ib + lane] = __expf(logt + Wr[c0 + lane]);
}

struct PrepIn { const float *W0, *dw0, *W1, *dw1, *W2, *dw2; };

// all three flows' preps in ONE launch: grid 3 * (2048+2048+64) = 12480
__global__ __launch_bounds__(64) void prep_mega(
    PrepIn p0, PrepIn p1, PrepIn p2,
    float* __restrict__ wn0T_all, float* __restrict__ eg0_all,
    __hip_bfloat16* __restrict__ wn1_all, float* __restrict__ e1_all,
    __hip_bfloat16* __restrict__ wn2b_all, float* __restrict__ e2_all)
{
    int blk = blockIdx.x;
    int lane = threadIdx.x;
    int f = blk / 4160;
    int rem = blk - f * 4160;
    PrepIn P = (f == 0) ? p0 : ((f == 1) ? p1 : p2);

    float* wn0T = wn0T_all + (size_t)f * DIMN * HIDF;
    float* eg0  = eg0_all  + (size_t)f * HIDF;
    __hip_bfloat16* wn1 = wn1_all + (size_t)f * HIDF * HIDF;
    float* e1   = e1_all   + (size_t)f * HIDF * 32;
    __hip_bfloat16* wn2b = wn2b_all + (size_t)f * DIMN * HIDF;
    float* e2   = e2_all   + (size_t)f * DIMN * 32;

    if (rem < HIDF) {
        prep_row<DIMN>(P.W0, P.dw0, wn0T, eg0, rem, lane, HIDF, 32, 1, 1, 0);
    } else if (rem < 2 * HIDF) {
        prep_row<HIDF>(P.W1, P.dw1, wn1, e1, rem - HIDF, lane, HIDF, 32, 32, 0, 1);
    } else {
        prep_row<HIDF>(P.W2, P.dw2, wn2b, e2, rem - 2 * HIDF, lane, DIMN, 1, 32, 0, 1);
    }
}

// ---------------------------------------------------------------------------
// gemm0_act: pre0 = x @ wn0T + b0 ; h0 = tanh(pre0) bf16;
// g0e[b,n] = eg0[n] * sech^2(pre0)  (bf16). grid (8, 64), 256 threads.
// ---------------------------------------------------------------------------
__global__ __launch_bounds__(256) void gemm0_act(
    const float* __restrict__ xin, const float* __restrict__ wn0T,
    const float* __restrict__ bias, const float* __restrict__ eg0,
    __hip_bfloat16* __restrict__ h0, __hip_bfloat16* __restrict__ g0e)
{
    __shared__ float xs[16][DIMN];
    int b0 = blockIdx.y * 16;
    {
        const float4* src = (const float4*)(xin + (size_t)b0 * DIMN);
        ((float4*)xs)[threadIdx.x] = src[threadIdx.x];
    }
    __syncthreads();
    int n = blockIdx.x * 256 + threadIdx.x;

    float acc[16];
#pragma unroll
    for (int j = 0; j < 16; ++j) acc[j] = 0.f;

#pragma unroll 4
    for (int c4 = 0; c4 < 16; ++c4) {
        int c = c4 * 4;
        float w0 = wn0T[(size_t)(c + 0) * HIDF + n];
        float w1 = wn0T[(size_t)(c + 1) * HIDF + n];
        float w2 = wn0T[(size_t)(c + 2) * HIDF + n];
        float w3 = wn0T[(size_t)(c + 3) * HIDF + n];
#pragma unroll
        for (int j = 0; j < 16; ++j) {
            float4 x4 = *(const float4*)&xs[j][c];
            acc[j] = fmaf(x4.x, w0, acc[j]);
            acc[j] = fmaf(x4.y, w1, acc[j]);
            acc[j] = fmaf(x4.z, w2, acc[j]);
            acc[j] = fmaf(x4.w, w3, acc[j]);
        }
    }
    float bv = bias[n], egv = eg0[n];
#pragma unroll
    for (int j = 0; j < 16; ++j) {
        float p = acc[j] + bv;
        float th, s2;
        tanh_sech2_(p, th, s2);
        size_t idx = (size_t)(b0 + j) * HIDF + n;
        h0[idx] = __float2bfloat16(th);
        g0e[idx] = __float2bfloat16(egv * s2);
    }
}

// ---------------------------------------------------------------------------
// gemm1_part: partial[kz][m][n] = sum_{k in chunk kz} h0[m,k]*wn1[n,k] (bf16)
// 128x128 tile, 4 waves each owning a 64x64 quadrant (4x4 16x16 frags),
// BK=64, XOR chunk swizzle, global_load_lds 16B staging.
// Triangular schedule: only the 40 live (jn,kz) pairs run, LPT-sorted
// (longest first) so CUs stay balanced. grid 320 = 40 pairs x 8 m-tiles.
// ---------------------------------------------------------------------------
__constant__ unsigned char G1_JN[40] = {
    3,4,5,6,7,7,8,8,9,9,10,10,11,11,11,12,12,12,13,13,13,14,14,14,
    15,15,15,15, 2,6,10,14, 1,5,9,13, 0,4,8,12 };
__constant__ unsigned char G1_KZ[40] = {
    0,0,0,0,0,1,0,1,0,1, 0, 1, 0, 1, 2, 0, 1, 2, 0, 1, 2, 0, 1, 2,
     0, 1, 2, 3, 0,1, 2, 3, 0,1,2,3, 0,1,2,3 };

#define G1BK 64
__global__ __launch_bounds__(256) void gemm1_part(
    const __hip_bfloat16* __restrict__ A, const __hip_bfloat16* __restrict__ B,
    __hip_bfloat16* __restrict__ part)
{
    const int K = HIDF, N = HIDF;
    int pr = blockIdx.x >> 3;      // pair index (LPT order, heavy first)
    int my = blockIdx.x & 7;       // m-tile
    int jn = G1_JN[pr];
    int kz = G1_KZ[pr];
    int kbase = kz * (K / SPLITK);
    int kend = (jn + 1) * 128 - kbase;          // live K within this chunk
    if (kend > K / SPLITK) kend = K / SPLITK;

    __shared__ short As[128 * 64];   // 16 KB [128 m][64 k] swizzled
    __shared__ short Bs[128 * 64];   // 16 KB [128 n][64 k] swizzled
    int tid = threadIdx.x;
    int lane = tid & 63;
    int wave = tid >> 6;
    int n0 = jn * 128;
    int m0 = my * 128;
    int wr = wave >> 1;   // m half (64 rows)
    int wc = wave & 1;    // n half (64 cols)

    int rf = lane & 15;
    int q = lane >> 4;    // 0..3

    const char* agp[4];
    const char* bgp[4];
    char* alds[4];
    char* blds[4];
#pragma unroll
    for (int s = 0; s < 4; ++s) {
        int c = tid + s * 256;
        int row = c >> 3;
        int kc = (c & 7) ^ (row & 7);
        agp[s] = (const char*)A + ((size_t)(m0 + row) * K + kbase) * 2 + kc * 16;
        bgp[s] = (const char*)B + ((size_t)(n0 + row) * K + kbase) * 2 + kc * 16;
        alds[s] = (char*)As + c * 16;
        blds[s] = (char*)Bs + c * 16;
    }

    floatx4 acc[4][4];
#pragma unroll
    for (int i = 0; i < 4; ++i)
#pragma unroll
        for (int j = 0; j < 4; ++j) acc[i][j] = (floatx4){0.f, 0.f, 0.f, 0.f};

    int rowA0 = wr * 64 + rf;
    int rowB0 = wc * 64 + rf;

    for (int k0 = 0; k0 < kend; k0 += G1BK) {
        size_t kb = (size_t)k0 * 2;
        __syncthreads();
#pragma unroll
        for (int s = 0; s < 4; ++s) {
            gl_lds16(agp[s] + kb, alds[s]);
            gl_lds16(bgp[s] + kb, blds[s]);
        }
        __syncthreads();

#pragma unroll
        for (int s = 0; s < 2; ++s) {
            short8 af[4], bfv[4];
#pragma unroll
            for (int i = 0; i < 4; ++i) {
                int row = rowA0 + i * 16;
                af[i] = *(const short8*)&As[row * 64 + (((s * 4 + q) ^ (row & 7)) * 8)];
            }
#pragma unroll
            for (int j = 0; j < 4; ++j) {
                int row = rowB0 + j * 16;
                bfv[j] = *(const short8*)&Bs[row * 64 + (((s * 4 + q) ^ (row & 7)) * 8)];
            }
#pragma unroll
            for (int i = 0; i < 4; ++i)
#pragma unroll
                for (int j = 0; j < 4; ++j)
                    acc[i][j] = __builtin_amdgcn_mfma_f32_16x16x32_bf16(af[i], bfv[j], acc[i][j], 0, 0, 0);
        }
    }

    __hip_bfloat16* pk = part + (size_t)kz * BATCH * HIDF;
    int col = lane & 15;
    int rq = (lane >> 4) * 4;
#pragma unroll
    for (int i = 0; i < 4; ++i) {
#pragma unroll
        for (int j = 0; j < 4; ++j) {
            int n = n0 + wc * 64 + j * 16 + col;
#pragma unroll
            for (int r = 0; r < 4; ++r) {
                int m = m0 + wr * 64 + i * 16 + rq + r;
                pk[(size_t)m * N + n] = __float2bfloat16(acc[i][j][r]);
            }
        }
    }
}

// ---------------------------------------------------------------------------
// act_grad_gemm2: per 64b x 64n tile:
//  Phase A: pre1 = sum_{p<np} part[p]+bias (np = bx/8+1 live partials,
//           uniform branches); h1 (bf16) -> LDS;
//           grad1e = sech^2(pre1) * sum_k E1[n,k]*g0e[b,(n&~31)+k]  -> global
//  Phase B: out2p[ntile][b][d] = h1_tile @ wn2b^T; MFMA skipped for
//           provably-zero j < jact0 = bx/8, but zeros still WRITTEN so the
//           fully-unrolled tails can read all 32 partials.
// ---------------------------------------------------------------------------
__global__ __launch_bounds__(256) void act_grad_gemm2(
    const __hip_bfloat16* __restrict__ part, const float* __restrict__ bias,
    const float* __restrict__ e1, const __hip_bfloat16* __restrict__ g0e,
    const __hip_bfloat16* __restrict__ wn2b,
    __hip_bfloat16* __restrict__ grad1e, float* __restrict__ out2p)
{
    __shared__ char smem[17408 + 8704 + 8192];
    float* g0s = (float*)smem;                          // 64 x 68 floats
    short* h1s = (short*)(smem + 17408);                // 64 x 68 shorts (pad)
    short* Bs2 = (short*)(smem + 17408 + 8704);         // 64 x 64 swizzled

    int tid = threadIdx.x;
    int lane = tid & 63;
    int wave = tid >> 6;
    int bx = blockIdx.x;
    int n0 = bx * 64;
    int b0 = blockIdx.y * 64;
    int np = (bx >> 3) + 1;      // live partials
    int jact0 = bx >> 3;         // first live output d-frag (d >= 2*bx)

    // early async stage of wn2b k-slice [64 d][n0..n0+64] (XOR swizzle)
    {
        int c0c = tid, c1c = tid + 256;
        int r0 = c0c >> 3, k0c = (c0c & 7) ^ (r0 & 7);
        int r1 = c1c >> 3, k1c = (c1c & 7) ^ (r1 & 7);
        gl_lds16((const char*)wn2b + ((size_t)r0 * HIDF + n0) * 2 + k0c * 16,
                 (char*)Bs2 + c0c * 16);
        gl_lds16((const char*)wn2b + ((size_t)r1 * HIDF + n0) * 2 + k1c * 16,
                 (char*)Bs2 + c1c * 16);
    }

    // stage g0e tile [64 b][64 c] bf16 -> f32 LDS (pad 68)
    for (int s = tid; s < 512; s += 256) {
        int row = s >> 3, c8 = s & 7;
        short8 v = *(const short8*)((const short*)g0e +
                                    (size_t)(b0 + row) * HIDF + n0 + c8 * 8);
        float4 lo = { bf2f(v[0]), bf2f(v[1]), bf2f(v[2]), bf2f(v[3]) };
        float4 hi = { bf2f(v[4]), bf2f(v[5]), bf2f(v[6]), bf2f(v[7]) };
        *(float4*)&g0s[row * 68 + c8 * 8] = lo;
        *(float4*)&g0s[row * 68 + c8 * 8 + 4] = hi;
    }

    int g = tid >> 6;        // b-group 0..3
    int nl = tid & 63;       // local n
    int n = n0 + nl;

    // E1 row for this n into registers (32 floats)
    float4 er[8];
    const float4* e1r = (const float4*)(e1 + (size_t)n * 32);
#pragma unroll
    for (int qq = 0; qq < 8; ++qq) er[qq] = e1r[qq];

    float bv = bias[n];
    int kb2 = nl & 32;
    const __hip_bfloat16* pp0 = part;
    const __hip_bfloat16* pp1 = part + (size_t)1 * BATCH * HIDF;
    const __hip_bfloat16* pp2 = part + (size_t)2 * BATCH * HIDF;
    const __hip_bfloat16* pp3 = part + (size_t)3 * BATCH * HIDF;

    __syncthreads();

    // Phase A
#pragma unroll
    for (int t = 0; t < 16; ++t) {
        int bl = g * 16 + t;
        int b = b0 + bl;
        size_t idx = (size_t)b * HIDF + n;
        float pre = bv + __bfloat162float(pp0[idx]);
        if (np > 1) pre += __bfloat162float(pp1[idx]);
        if (np > 2) pre += __bfloat162float(pp2[idx]);
        if (np > 3) pre += __bfloat162float(pp3[idx]);
        float th, s2;
        tanh_sech2_(pre, th, s2);
        const float* g0row = &g0s[bl * 68 + kb2];
        float dot = 0.f;
#pragma unroll
        for (int qq = 0; qq < 8; ++qq) {
            float4 gv = *(const float4*)&g0row[qq * 4];
            dot = fmaf(gv.x, er[qq].x, dot);
            dot = fmaf(gv.y, er[qq].y, dot);
            dot = fmaf(gv.z, er[qq].z, dot);
            dot = fmaf(gv.w, er[qq].w, dot);
        }
        __hip_bfloat16 thb = __float2bfloat16(th);
        h1s[bl * 68 + nl] = *(const short*)&thb;
        grad1e[idx] = __float2bfloat16(dot * s2);
    }
    __syncthreads();

    // Phase B: 64b x 64d GEMM over K=64 (the nl slice); skip dead MFMAs
    int rf = lane & 15;
    int q = lane >> 4;
    floatx4 acc2[4];
#pragma unroll
    for (int j = 0; j < 4; ++j) acc2[j] = (floatx4){0.f, 0.f, 0.f, 0.f};

#pragma unroll
    for (int s = 0; s < 2; ++s) {
        int rowa = wave * 16 + rf;
        short8 af = *(const short8*)&h1s[rowa * 68 + s * 32 + q * 8];
#pragma unroll
        for (int j = 0; j < 4; ++j) {
            if (j >= jact0) {
                int rowb = j * 16 + rf;
                int cp = (s * 4 + q) ^ (rowb & 7);
                short8 bfv = *(const short8*)&Bs2[rowb * 64 + cp * 8];
                acc2[j] = __builtin_amdgcn_mfma_f32_16x16x32_bf16(af, bfv, acc2[j], 0, 0, 0);
            }
        }
    }

    float* outk = out2p + (size_t)bx * BATCH * DIMN;
    int col = lane & 15;
    int rq = (lane >> 4) * 4;
#pragma unroll
    for (int j = 0; j < 4; ++j) {
#pragma unroll
        for (int r = 0; r < 4; ++r) {
            int m = b0 + wave * 16 + rq + r;
            outk[(size_t)m * DIMN + j * 16 + col] = acc2[j][r];
        }
    }
}

// ---------------------------------------------------------------------------
// tail_trans: one wave per batch row. Single-pass partial reduction:
//  o = b2 + sum_p out2p[p][b][n]; xo = gate-mix; x_next[b][63-n] = xo;
//  gF = log(sum_k E2[n,k]*grad1e[b,n*32+k]); ldj write/accum.
// grid 256 (4 b per block), 256 threads.
// ---------------------------------------------------------------------------
__global__ __launch_bounds__(256) void tail_trans(
    const float* __restrict__ out2p, const float* __restrict__ b2,
    const float* __restrict__ e2, const __hip_bfloat16* __restrict__ grad1e,
    const float* __restrict__ x_cur, const float* __restrict__ gate,
    float* __restrict__ x_next, float* __restrict__ ldj, int accum_ldj)
{
    int tid = threadIdx.x;
    int b = blockIdx.x * 4 + (tid >> 6);
    int n = tid & 63;

    float o = b2[n];
#pragma unroll
    for (int p = 0; p < NT2; ++p)
        o += out2p[(size_t)p * BATCH * DIMN + (size_t)b * DIMN + n];

    float gt = gate[0];
    float sg = 1.f / (1.f + __expf(-gt));
    float xo = sg * o + (1.f - sg) * x_cur[(size_t)b * DIMN + n];
    x_next[(size_t)b * DIMN + (63 - n)] = xo;

    const short8* gr = (const short8*)((const short*)grad1e + (size_t)b * HIDF + n * 32);
    const float4* gc = (const float4*)(e2 + n * 32);
    float s = 0.f;
#pragma unroll
    for (int q = 0; q < 4; ++q) {
        short8 a8 = gr[q];
        float4 c0 = gc[2 * q], c1 = gc[2 * q + 1];
        s = fmaf(bf2f(a8[0]), c0.x, s);
        s = fmaf(bf2f(a8[1]), c0.y, s);
        s = fmaf(bf2f(a8[2]), c0.z, s);
        s = fmaf(bf2f(a8[3]), c0.w, s);
        s = fmaf(bf2f(a8[4]), c1.x, s);
        s = fmaf(bf2f(a8[5]), c1.y, s);
        s = fmaf(bf2f(a8[6]), c1.z, s);
        s = fmaf(bf2f(a8[7]), c1.w, s);
    }
    float gF = __logf(fmaxf(s, 1e-45f));
    float contrib = softplusf_(gF + gt) - softplusf_(gt);
    for (int off = 32; off > 0; off >>= 1) contrib += __shfl_xor(contrib, off, 64);
    if (n == 0) ldj[b] = accum_ldj ? (ldj[b] + contrib) : contrib;
}

// ---------------------------------------------------------------------------
// tail_final (flow 2): out[b] = ldj[b] + sum_n(gF - 0.5*o^2 - 0.5*log(2pi))
// ---------------------------------------------------------------------------
__global__ __launch_bounds__(256) void tail_final(
    const float* __restrict__ out2p, const float* __restrict__ b2,
    const float* __restrict__ e2, const __hip_bfloat16* __restrict__ grad1e,
    const float* __restrict__ ldj, float* __restrict__ out)
{
    int tid = threadIdx.x;
    int b = blockIdx.x * 4 + (tid >> 6);
    int n = tid & 63;

    float o = b2[n];
#pragma unroll
    for (int p = 0; p < NT2; ++p)
        o += out2p[(size_t)p * BATCH * DIMN + (size_t)b * DIMN + n];

    const short8* gr = (const short8*)((const short*)grad1e + (size_t)b * HIDF + n * 32);
    const float4* gc = (const float4*)(e2 + n * 32);
    float s = 0.f;
#pragma unroll
    for (int q = 0; q < 4; ++q) {
        short8 a8 = gr[q];
        float4 c0 = gc[2 * q], c1 = gc[2 * q + 1];
        s = fmaf(bf2f(a8[0]), c0.x, s);
        s = fmaf(bf2f(a8[1]), c0.y, s);
        s = fmaf(bf2f(a8[2]), c0.z, s);
        s = fmaf(bf2f(a8[3]), c0.w, s);
        s = fmaf(bf2f(a8[4]), c1.x, s);
        s = fmaf(bf2f(a8[5]), c1.y, s);
        s = fmaf(bf2f(a8[6]), c1.z, s);
        s = fmaf(bf2f(a8[7]), c1.w, s);
    }
    float gF = __logf(fmaxf(s, 1e-45f));

    float contrib = gF - 0.5f * o * o - 0.91893853320467274f; // -0.5*log(2pi)
    for (int off = 32; off > 0; off >>= 1) contrib += __shfl_xor(contrib, off, 64);
    if (n == 0) out[b] = ldj[b] + contrib;
}

// ---------------------------------------------------------------------------
extern "C" void kernel_launch(void* const* d_in, const int* in_sizes, int n_in,
                              void* d_out, int out_size, void* d_ws, size_t ws_size,
                              hipStream_t stream)
{
    (void)in_sizes; (void)n_in; (void)out_size; (void)ws_size;

    const float* x = (const float*)d_in[0];
    const float* gates[2] = { (const float*)d_in[28], (const float*)d_in[29] };

    char* ws = (char*)d_ws;
    size_t ofs = 0;
    auto alloc = [&](size_t bytes) { char* p = ws + ofs; ofs += (bytes + 255) & ~(size_t)255; return p; };

    __hip_bfloat16* wn1_all  = (__hip_bfloat16*)alloc((size_t)3 * HIDF * HIDF * 2);  // 24 MB
    __hip_bfloat16* wn2b_all = (__hip_bfloat16*)alloc((size_t)3 * DIMN * HIDF * 2);
    float* wn0T_all = (float*)alloc((size_t)3 * DIMN * HIDF * 4);
    float* eg0_all  = (float*)alloc((size_t)3 * HIDF * 4);
    float* e1_all   = (float*)alloc((size_t)3 * HIDF * 32 * 4);
    float* e2_all   = (float*)alloc((size_t)3 * DIMN * 32 * 4);
    __hip_bfloat16* h0   = (__hip_bfloat16*)alloc((size_t)BATCH * HIDF * 2);
    __hip_bfloat16* part = (__hip_bfloat16*)alloc((size_t)SPLITK * BATCH * HIDF * 2); // 16 MB
    __hip_bfloat16* g0e    = (__hip_bfloat16*)alloc((size_t)BATCH * HIDF * 2);
    __hip_bfloat16* grad1e = (__hip_bfloat16*)alloc((size_t)BATCH * HIDF * 2);
    float* out2p  = (float*)alloc((size_t)NT2 * BATCH * DIMN * 4);                    // 8 MB
    float* x1     = (float*)alloc((size_t)BATCH * DIMN * 4);
    float* x2     = (float*)alloc((size_t)BATCH * DIMN * 4);
    float* ldj    = (float*)alloc(BATCH * 4);
    float* outp   = (float*)d_out;

    auto W = [&](int f, int i) { return (const float*)d_in[1 + f * 9 + i]; };

    PrepIn p0 = { W(0,0), W(0,1), W(0,3), W(0,4), W(0,6), W(0,7) };
    PrepIn p1 = { W(1,0), W(1,1), W(1,3), W(1,4), W(1,6), W(1,7) };
    PrepIn p2 = { W(2,0), W(2,1), W(2,3), W(2,4), W(2,6), W(2,7) };

    prep_mega<<<dim3(3 * 4160), dim3(64), 0, stream>>>(
        p0, p1, p2, wn0T_all, eg0_all, wn1_all, e1_all, wn2b_all, e2_all);

    gemm0_act<<<dim3(8, BATCH / 16), dim3(256), 0, stream>>>(
        x, wn0T_all, W(0,2), eg0_all, h0, g0e);

    const float* xcur = x;
    float* xnexts[2] = { x1, x2 };

    for (int f = 0; f < 3; ++f) {
        size_t fo1 = (size_t)f * HIDF * HIDF;
        size_t fo2 = (size_t)f * DIMN * HIDF;

        gemm1_part<<<dim3(320), dim3(256), 0, stream>>>(
            h0, wn1_all + fo1, part);

        act_grad_gemm2<<<dim3(HIDF / 64, BATCH / 64), dim3(256), 0, stream>>>(
            part, W(f,5), e1_all + (size_t)f * HIDF * 32, g0e,
            wn2b_all + fo2, grad1e, out2p);

        if (f < 2) {
            tail_trans<<<dim3(BATCH / 4), dim3(256), 0, stream>>>(
                out2p, W(f,8), e2_all + (size_t)f * DIMN * 32, grad1e,
                xcur, gates[f], xnexts[f], ldj, f);

            gemm0_act<<<dim3(8, BATCH / 16), dim3(256), 0, stream>>>(
                xnexts[f], wn0T_all + (size_t)(f + 1) * DIMN * HIDF, W(f + 1, 2),
                eg0_all + (size_t)(f + 1) * HIDF, h0, g0e);

            xcur = xnexts[f];
        } else {
            tail_final<<<dim3(BATCH / 4), dim3(256), 0, stream>>>(
                out2p, W(2,8), e2_all + (size_t)2 * DIMN * 32, grad1e, ldj, outp);
        }
    }
}

// Round 4
// 291.361 us; speedup vs baseline: 1.1782x; 1.1361x over previous
//
#include <hip/hip_runtime.h>
#include <hip/hip_bf16.h>
#include <math.h>

// ---------------------------------------------------------------------------
// BNAF flow (DIM=64, HID=32, B=1024).  R19: R16 base (291us) + gemm1 LPT
// live-block schedule (2176 of 4096 K-iters, longest-first) + BRANCH-FREE
// act_grad partial reads (4 unconditional loads, dead partials redirected
// to the always-live p0 plane and masked by 0/1 floats -> R16's MLP shape).
// Phase B unconditional (R16 form). 13 dispatches.
// ---------------------------------------------------------------------------

#define DIMN 64
#define BATCH 1024
#define HIDF 2048   // DIM*HID
#define SPLITK 4
#define NT2 32      // out2 partial count (= HIDF/64 n-tiles)

typedef __attribute__((ext_vector_type(8))) short short8;
typedef __attribute__((ext_vector_type(4))) float floatx4;

__device__ __forceinline__ float softplusf_(float t) {
    return fmaxf(t, 0.f) + log1pf(__expf(-fabsf(t)));
}

__device__ __forceinline__ float bf2f(short v) {
    union { unsigned u; float f; } x;
    x.u = ((unsigned)(unsigned short)v) << 16;
    return x.f;
}

__device__ __forceinline__ void gl_lds16(const void* g, void* l) {
    __builtin_amdgcn_global_load_lds(
        (const __attribute__((address_space(1))) unsigned int*)g,
        (__attribute__((address_space(3))) unsigned int*)l, 16, 0, 0);
}

// tanh + sech^2 from ONE exp:  t = e^{-2|p|}; tanh = sign(p)(1-t)/(1+t);
// sech^2 = 4t/(1+t)^2.
__device__ __forceinline__ void tanh_sech2_(float p, float& th, float& s2) {
    float t = __expf(-2.f * fabsf(p));
    float opt = 1.f + t;
    float inv = 1.f / opt;
    th = copysignf((1.f - t) * inv, p);
    s2 = 4.f * t * inv * inv;
}

// ---------------------------------------------------------------------------
// prep row worker: one wave per output row r of W (out_f x INF).
//  wn = exp(dw)*w/sqrt(wsn); eg[r*ib+k] = exp(dw + W[r][c0+k] - 0.5 log wsn)
// ---------------------------------------------------------------------------
template<int INF>
__device__ __forceinline__ void prep_row(
    const float* __restrict__ W, const float* __restrict__ dw,
    void* __restrict__ wn_out, float* __restrict__ eg,
    int r, int lane, int out_f, int ob, int ib, int transpose, int bf16out)
{
    constexpr int NI = INF / 64;
    int d = r / ob;
    int c0 = d * ib;
    int c1 = c0 + ib;
    const float* Wr = W + (size_t)r * INF;

    float vv[NI];
    float ss = 0.f;
#pragma unroll
    for (int i = 0; i < NI; ++i) {
        int c = lane + i * 64;
        float wraw = Wr[c];
        float wv = (c < c0) ? wraw : ((c < c1) ? __expf(wraw) : 0.f);
        vv[i] = wv;
        ss += wv * wv;
    }
    for (int off = 32; off > 0; off >>= 1) ss += __shfl_xor(ss, off, 64);

    float dwr = dw[r];
    float scale = __expf(dwr) / sqrtf(ss);
    float logt = dwr - 0.5f * __logf(ss);

#pragma unroll
    for (int i = 0; i < NI; ++i) {
        int c = lane + i * 64;
        float val = scale * vv[i];
        if (bf16out) {
            ((__hip_bfloat16*)wn_out)[(size_t)r * INF + c] = __float2bfloat16(val);
        } else if (transpose) {
            ((float*)wn_out)[(size_t)c * out_f + r] = val;
        } else {
            ((float*)wn_out)[(size_t)r * INF + c] = val;
        }
    }
    if (lane < ib) eg[(size_t)r * ib + lane] = __expf(logt + Wr[c0 + lane]);
}

struct PrepIn { const float *W0, *dw0, *W1, *dw1, *W2, *dw2; };

// all three flows' preps in ONE launch: grid 3 * (2048+2048+64) = 12480
__global__ __launch_bounds__(64) void prep_mega(
    PrepIn p0, PrepIn p1, PrepIn p2,
    float* __restrict__ wn0T_all, float* __restrict__ eg0_all,
    __hip_bfloat16* __restrict__ wn1_all, float* __restrict__ e1_all,
    __hip_bfloat16* __restrict__ wn2b_all, float* __restrict__ e2_all)
{
    int blk = blockIdx.x;
    int lane = threadIdx.x;
    int f = blk / 4160;
    int rem = blk - f * 4160;
    PrepIn P = (f == 0) ? p0 : ((f == 1) ? p1 : p2);

    float* wn0T = wn0T_all + (size_t)f * DIMN * HIDF;
    float* eg0  = eg0_all  + (size_t)f * HIDF;
    __hip_bfloat16* wn1 = wn1_all + (size_t)f * HIDF * HIDF;
    float* e1   = e1_all   + (size_t)f * HIDF * 32;
    __hip_bfloat16* wn2b = wn2b_all + (size_t)f * DIMN * HIDF;
    float* e2   = e2_all   + (size_t)f * DIMN * 32;

    if (rem < HIDF) {
        prep_row<DIMN>(P.W0, P.dw0, wn0T, eg0, rem, lane, HIDF, 32, 1, 1, 0);
    } else if (rem < 2 * HIDF) {
        prep_row<HIDF>(P.W1, P.dw1, wn1, e1, rem - HIDF, lane, HIDF, 32, 32, 0, 1);
    } else {
        prep_row<HIDF>(P.W2, P.dw2, wn2b, e2, rem - 2 * HIDF, lane, DIMN, 1, 32, 0, 1);
    }
}

// ---------------------------------------------------------------------------
// gemm0_act: pre0 = x @ wn0T + b0 ; h0 = tanh(pre0) bf16;
// g0e[b,n] = eg0[n] * sech^2(pre0)  (bf16). grid (8, 64), 256 threads.
// ---------------------------------------------------------------------------
__global__ __launch_bounds__(256) void gemm0_act(
    const float* __restrict__ xin, const float* __restrict__ wn0T,
    const float* __restrict__ bias, const float* __restrict__ eg0,
    __hip_bfloat16* __restrict__ h0, __hip_bfloat16* __restrict__ g0e)
{
    __shared__ float xs[16][DIMN];
    int b0 = blockIdx.y * 16;
    {
        const float4* src = (const float4*)(xin + (size_t)b0 * DIMN);
        ((float4*)xs)[threadIdx.x] = src[threadIdx.x];
    }
    __syncthreads();
    int n = blockIdx.x * 256 + threadIdx.x;

    float acc[16];
#pragma unroll
    for (int j = 0; j < 16; ++j) acc[j] = 0.f;

#pragma unroll 4
    for (int c4 = 0; c4 < 16; ++c4) {
        int c = c4 * 4;
        float w0 = wn0T[(size_t)(c + 0) * HIDF + n];
        float w1 = wn0T[(size_t)(c + 1) * HIDF + n];
        float w2 = wn0T[(size_t)(c + 2) * HIDF + n];
        float w3 = wn0T[(size_t)(c + 3) * HIDF + n];
#pragma unroll
        for (int j = 0; j < 16; ++j) {
            float4 x4 = *(const float4*)&xs[j][c];
            acc[j] = fmaf(x4.x, w0, acc[j]);
            acc[j] = fmaf(x4.y, w1, acc[j]);
            acc[j] = fmaf(x4.z, w2, acc[j]);
            acc[j] = fmaf(x4.w, w3, acc[j]);
        }
    }
    float bv = bias[n], egv = eg0[n];
#pragma unroll
    for (int j = 0; j < 16; ++j) {
        float p = acc[j] + bv;
        float th, s2;
        tanh_sech2_(p, th, s2);
        size_t idx = (size_t)(b0 + j) * HIDF + n;
        h0[idx] = __float2bfloat16(th);
        g0e[idx] = __float2bfloat16(egv * s2);
    }
}

// ---------------------------------------------------------------------------
// gemm1_part: partial[kz][m][n] = sum_{k in chunk kz} h0[m,k]*wn1[n,k] (bf16)
// 128x128 tile, 4 waves each owning a 64x64 quadrant (4x4 16x16 frags),
// BK=64, XOR chunk swizzle, global_load_lds 16B staging.
// Triangular schedule: only the 40 live (jn,kz) pairs run, LPT-sorted
// (longest first) so CUs stay balanced. grid 320 = 40 pairs x 8 m-tiles.
// ---------------------------------------------------------------------------
__constant__ unsigned char G1_JN[40] = {
    3,4,5,6,7,7,8,8,9,9,10,10,11,11,11,12,12,12,13,13,13,14,14,14,
    15,15,15,15, 2,6,10,14, 1,5,9,13, 0,4,8,12 };
__constant__ unsigned char G1_KZ[40] = {
    0,0,0,0,0,1,0,1,0,1, 0, 1, 0, 1, 2, 0, 1, 2, 0, 1, 2, 0, 1, 2,
     0, 1, 2, 3, 0,1, 2, 3, 0,1,2,3, 0,1,2,3 };

#define G1BK 64
__global__ __launch_bounds__(256) void gemm1_part(
    const __hip_bfloat16* __restrict__ A, const __hip_bfloat16* __restrict__ B,
    __hip_bfloat16* __restrict__ part)
{
    const int K = HIDF, N = HIDF;
    int pr = blockIdx.x >> 3;      // pair index (LPT order, heavy first)
    int my = blockIdx.x & 7;       // m-tile
    int jn = G1_JN[pr];
    int kz = G1_KZ[pr];
    int kbase = kz * (K / SPLITK);
    int kend = (jn + 1) * 128 - kbase;          // live K within this chunk
    if (kend > K / SPLITK) kend = K / SPLITK;

    __shared__ short As[128 * 64];   // 16 KB [128 m][64 k] swizzled
    __shared__ short Bs[128 * 64];   // 16 KB [128 n][64 k] swizzled
    int tid = threadIdx.x;
    int lane = tid & 63;
    int wave = tid >> 6;
    int n0 = jn * 128;
    int m0 = my * 128;
    int wr = wave >> 1;   // m half (64 rows)
    int wc = wave & 1;    // n half (64 cols)

    int rf = lane & 15;
    int q = lane >> 4;    // 0..3

    const char* agp[4];
    const char* bgp[4];
    char* alds[4];
    char* blds[4];
#pragma unroll
    for (int s = 0; s < 4; ++s) {
        int c = tid + s * 256;
        int row = c >> 3;
        int kc = (c & 7) ^ (row & 7);
        agp[s] = (const char*)A + ((size_t)(m0 + row) * K + kbase) * 2 + kc * 16;
        bgp[s] = (const char*)B + ((size_t)(n0 + row) * K + kbase) * 2 + kc * 16;
        alds[s] = (char*)As + c * 16;
        blds[s] = (char*)Bs + c * 16;
    }

    floatx4 acc[4][4];
#pragma unroll
    for (int i = 0; i < 4; ++i)
#pragma unroll
        for (int j = 0; j < 4; ++j) acc[i][j] = (floatx4){0.f, 0.f, 0.f, 0.f};

    int rowA0 = wr * 64 + rf;
    int rowB0 = wc * 64 + rf;

    for (int k0 = 0; k0 < kend; k0 += G1BK) {
        size_t kb = (size_t)k0 * 2;
        __syncthreads();
#pragma unroll
        for (int s = 0; s < 4; ++s) {
            gl_lds16(agp[s] + kb, alds[s]);
            gl_lds16(bgp[s] + kb, blds[s]);
        }
        __syncthreads();

#pragma unroll
        for (int s = 0; s < 2; ++s) {
            short8 af[4], bfv[4];
#pragma unroll
            for (int i = 0; i < 4; ++i) {
                int row = rowA0 + i * 16;
                af[i] = *(const short8*)&As[row * 64 + (((s * 4 + q) ^ (row & 7)) * 8)];
            }
#pragma unroll
            for (int j = 0; j < 4; ++j) {
                int row = rowB0 + j * 16;
                bfv[j] = *(const short8*)&Bs[row * 64 + (((s * 4 + q) ^ (row & 7)) * 8)];
            }
#pragma unroll
            for (int i = 0; i < 4; ++i)
#pragma unroll
                for (int j = 0; j < 4; ++j)
                    acc[i][j] = __builtin_amdgcn_mfma_f32_16x16x32_bf16(af[i], bfv[j], acc[i][j], 0, 0, 0);
        }
    }

    __hip_bfloat16* pk = part + (size_t)kz * BATCH * HIDF;
    int col = lane & 15;
    int rq = (lane >> 4) * 4;
#pragma unroll
    for (int i = 0; i < 4; ++i) {
#pragma unroll
        for (int j = 0; j < 4; ++j) {
            int n = n0 + wc * 64 + j * 16 + col;
#pragma unroll
            for (int r = 0; r < 4; ++r) {
                int m = m0 + wr * 64 + i * 16 + rq + r;
                pk[(size_t)m * N + n] = __float2bfloat16(acc[i][j][r]);
            }
        }
    }
}

// ---------------------------------------------------------------------------
// act_grad_gemm2: per 64b x 64n tile:
//  Phase A: pre1 = sum_p mask[p]*part[p']+bias -- 4 UNCONDITIONAL loads
//           (dead partials redirected to the always-live p0 plane, masked
//           by 0/1 floats; same MLP shape as R16); h1 (bf16) -> LDS;
//           grad1e = sech^2(pre1) * sum_k E1[n,k]*g0e[b,(n&~31)+k] -> global
//  Phase B: out2p[ntile][b][d] = h1_tile @ wn2b^T (unconditional, R16 form)
// ---------------------------------------------------------------------------
__global__ __launch_bounds__(256) void act_grad_gemm2(
    const __hip_bfloat16* __restrict__ part, const float* __restrict__ bias,
    const float* __restrict__ e1, const __hip_bfloat16* __restrict__ g0e,
    const __hip_bfloat16* __restrict__ wn2b,
    __hip_bfloat16* __restrict__ grad1e, float* __restrict__ out2p)
{
    __shared__ char smem[17408 + 8704 + 8192];
    float* g0s = (float*)smem;                          // 64 x 68 floats
    short* h1s = (short*)(smem + 17408);                // 64 x 68 shorts (pad)
    short* Bs2 = (short*)(smem + 17408 + 8704);         // 64 x 64 swizzled

    int tid = threadIdx.x;
    int lane = tid & 63;
    int wave = tid >> 6;
    int bx = blockIdx.x;
    int n0 = bx * 64;
    int b0 = blockIdx.y * 64;
    int np = (bx >> 3) + 1;      // live partials (1..4)

    // early async stage of wn2b k-slice [64 d][n0..n0+64] (XOR swizzle)
    {
        int c0c = tid, c1c = tid + 256;
        int r0 = c0c >> 3, k0c = (c0c & 7) ^ (r0 & 7);
        int r1 = c1c >> 3, k1c = (c1c & 7) ^ (r1 & 7);
        gl_lds16((const char*)wn2b + ((size_t)r0 * HIDF + n0) * 2 + k0c * 16,
                 (char*)Bs2 + c0c * 16);
        gl_lds16((const char*)wn2b + ((size_t)r1 * HIDF + n0) * 2 + k1c * 16,
                 (char*)Bs2 + c1c * 16);
    }

    // stage g0e tile [64 b][64 c] bf16 -> f32 LDS (pad 68)
    for (int s = tid; s < 512; s += 256) {
        int row = s >> 3, c8 = s & 7;
        short8 v = *(const short8*)((const short*)g0e +
                                    (size_t)(b0 + row) * HIDF + n0 + c8 * 8);
        float4 lo = { bf2f(v[0]), bf2f(v[1]), bf2f(v[2]), bf2f(v[3]) };
        float4 hi = { bf2f(v[4]), bf2f(v[5]), bf2f(v[6]), bf2f(v[7]) };
        *(float4*)&g0s[row * 68 + c8 * 8] = lo;
        *(float4*)&g0s[row * 68 + c8 * 8 + 4] = hi;
    }

    int g = tid >> 6;        // b-group 0..3
    int nl = tid & 63;       // local n
    int n = n0 + nl;

    // E1 row for this n into registers (32 floats)
    float4 er[8];
    const float4* e1r = (const float4*)(e1 + (size_t)n * 32);
#pragma unroll
    for (int qq = 0; qq < 8; ++qq) er[qq] = e1r[qq];

    float bv = bias[n];
    int kb2 = nl & 32;
    // Branch-free partial plane selection: dead planes -> p0 (live, L2-hot),
    // contribution masked by 0/1 floats. All 4 loads always issue (MLP).
    const __hip_bfloat16* pp0 = part;
    const __hip_bfloat16* pp1 = (np > 1) ? part + (size_t)1 * BATCH * HIDF : part;
    const __hip_bfloat16* pp2 = (np > 2) ? part + (size_t)2 * BATCH * HIDF : part;
    const __hip_bfloat16* pp3 = (np > 3) ? part + (size_t)3 * BATCH * HIDF : part;
    float m1 = (np > 1) ? 1.f : 0.f;
    float m2 = (np > 2) ? 1.f : 0.f;
    float m3 = (np > 3) ? 1.f : 0.f;

    __syncthreads();

    // Phase A
#pragma unroll
    for (int t = 0; t < 16; ++t) {
        int bl = g * 16 + t;
        int b = b0 + bl;
        size_t idx = (size_t)b * HIDF + n;
        float l0 = __bfloat162float(pp0[idx]);
        float l1 = __bfloat162float(pp1[idx]);
        float l2 = __bfloat162float(pp2[idx]);
        float l3 = __bfloat162float(pp3[idx]);
        float pre = bv + l0;
        pre = fmaf(m1, l1, pre);
        pre = fmaf(m2, l2, pre);
        pre = fmaf(m3, l3, pre);
        float th, s2;
        tanh_sech2_(pre, th, s2);
        const float* g0row = &g0s[bl * 68 + kb2];
        float dot = 0.f;
#pragma unroll
        for (int qq = 0; qq < 8; ++qq) {
            float4 gv = *(const float4*)&g0row[qq * 4];
            dot = fmaf(gv.x, er[qq].x, dot);
            dot = fmaf(gv.y, er[qq].y, dot);
            dot = fmaf(gv.z, er[qq].z, dot);
            dot = fmaf(gv.w, er[qq].w, dot);
        }
        __hip_bfloat16 thb = __float2bfloat16(th);
        h1s[bl * 68 + nl] = *(const short*)&thb;
        grad1e[idx] = __float2bfloat16(dot * s2);
    }
    __syncthreads();

    // Phase B: 64b x 64d GEMM over K=64 (the nl slice)
    int rf = lane & 15;
    int q = lane >> 4;
    floatx4 acc2[4];
#pragma unroll
    for (int j = 0; j < 4; ++j) acc2[j] = (floatx4){0.f, 0.f, 0.f, 0.f};

#pragma unroll
    for (int s = 0; s < 2; ++s) {
        int rowa = wave * 16 + rf;
        short8 af = *(const short8*)&h1s[rowa * 68 + s * 32 + q * 8];
#pragma unroll
        for (int j = 0; j < 4; ++j) {
            int rowb = j * 16 + rf;
            int cp = (s * 4 + q) ^ (rowb & 7);
            short8 bfv = *(const short8*)&Bs2[rowb * 64 + cp * 8];
            acc2[j] = __builtin_amdgcn_mfma_f32_16x16x32_bf16(af, bfv, acc2[j], 0, 0, 0);
        }
    }

    float* outk = out2p + (size_t)bx * BATCH * DIMN;
    int col = lane & 15;
    int rq = (lane >> 4) * 4;
#pragma unroll
    for (int j = 0; j < 4; ++j) {
#pragma unroll
        for (int r = 0; r < 4; ++r) {
            int m = b0 + wave * 16 + rq + r;
            outk[(size_t)m * DIMN + j * 16 + col] = acc2[j][r];
        }
    }
}

// ---------------------------------------------------------------------------
// tail_trans: one wave per batch row. Single-pass partial reduction:
//  o = b2 + sum_p out2p[p][b][n]; xo = gate-mix; x_next[b][63-n] = xo;
//  gF = log(sum_k E2[n,k]*grad1e[b,n*32+k]); ldj write/accum.
// grid 256 (4 b per block), 256 threads.
// ---------------------------------------------------------------------------
__global__ __launch_bounds__(256) void tail_trans(
    const float* __restrict__ out2p, const float* __restrict__ b2,
    const float* __restrict__ e2, const __hip_bfloat16* __restrict__ grad1e,
    const float* __restrict__ x_cur, const float* __restrict__ gate,
    float* __restrict__ x_next, float* __restrict__ ldj, int accum_ldj)
{
    int tid = threadIdx.x;
    int b = blockIdx.x * 4 + (tid >> 6);
    int n = tid & 63;

    float o = b2[n];
#pragma unroll
    for (int p = 0; p < NT2; ++p)
        o += out2p[(size_t)p * BATCH * DIMN + (size_t)b * DIMN + n];

    float gt = gate[0];
    float sg = 1.f / (1.f + __expf(-gt));
    float xo = sg * o + (1.f - sg) * x_cur[(size_t)b * DIMN + n];
    x_next[(size_t)b * DIMN + (63 - n)] = xo;

    const short8* gr = (const short8*)((const short*)grad1e + (size_t)b * HIDF + n * 32);
    const float4* gc = (const float4*)(e2 + n * 32);
    float s = 0.f;
#pragma unroll
    for (int q = 0; q < 4; ++q) {
        short8 a8 = gr[q];
        float4 c0 = gc[2 * q], c1 = gc[2 * q + 1];
        s = fmaf(bf2f(a8[0]), c0.x, s);
        s = fmaf(bf2f(a8[1]), c0.y, s);
        s = fmaf(bf2f(a8[2]), c0.z, s);
        s = fmaf(bf2f(a8[3]), c0.w, s);
        s = fmaf(bf2f(a8[4]), c1.x, s);
        s = fmaf(bf2f(a8[5]), c1.y, s);
        s = fmaf(bf2f(a8[6]), c1.z, s);
        s = fmaf(bf2f(a8[7]), c1.w, s);
    }
    float gF = __logf(fmaxf(s, 1e-45f));
    float contrib = softplusf_(gF + gt) - softplusf_(gt);
    for (int off = 32; off > 0; off >>= 1) contrib += __shfl_xor(contrib, off, 64);
    if (n == 0) ldj[b] = accum_ldj ? (ldj[b] + contrib) : contrib;
}

// ---------------------------------------------------------------------------
// tail_final (flow 2): out[b] = ldj[b] + sum_n(gF - 0.5*o^2 - 0.5*log(2pi))
// ---------------------------------------------------------------------------
__global__ __launch_bounds__(256) void tail_final(
    const float* __restrict__ out2p, const float* __restrict__ b2,
    const float* __restrict__ e2, const __hip_bfloat16* __restrict__ grad1e,
    const float* __restrict__ ldj, float* __restrict__ out)
{
    int tid = threadIdx.x;
    int b = blockIdx.x * 4 + (tid >> 6);
    int n = tid & 63;

    float o = b2[n];
#pragma unroll
    for (int p = 0; p < NT2; ++p)
        o += out2p[(size_t)p * BATCH * DIMN + (size_t)b * DIMN + n];

    const short8* gr = (const short8*)((const short*)grad1e + (size_t)b * HIDF + n * 32);
    const float4* gc = (const float4*)(e2 + n * 32);
    float s = 0.f;
#pragma unroll
    for (int q = 0; q < 4; ++q) {
        short8 a8 = gr[q];
        float4 c0 = gc[2 * q], c1 = gc[2 * q + 1];
        s = fmaf(bf2f(a8[0]), c0.x, s);
        s = fmaf(bf2f(a8[1]), c0.y, s);
        s = fmaf(bf2f(a8[2]), c0.z, s);
        s = fmaf(bf2f(a8[3]), c0.w, s);
        s = fmaf(bf2f(a8[4]), c1.x, s);
        s = fmaf(bf2f(a8[5]), c1.y, s);
        s = fmaf(bf2f(a8[6]), c1.z, s);
        s = fmaf(bf2f(a8[7]), c1.w, s);
    }
    float gF = __logf(fmaxf(s, 1e-45f));

    float contrib = gF - 0.5f * o * o - 0.91893853320467274f; // -0.5*log(2pi)
    for (int off = 32; off > 0; off >>= 1) contrib += __shfl_xor(contrib, off, 64);
    if (n == 0) out[b] = ldj[b] + contrib;
}

// ---------------------------------------------------------------------------
extern "C" void kernel_launch(void* const* d_in, const int* in_sizes, int n_in,
                              void* d_out, int out_size, void* d_ws, size_t ws_size,
                              hipStream_t stream)
{
    (void)in_sizes; (void)n_in; (void)out_size; (void)ws_size;

    const float* x = (const float*)d_in[0];
    const float* gates[2] = { (const float*)d_in[28], (const float*)d_in[29] };

    char* ws = (char*)d_ws;
    size_t ofs = 0;
    auto alloc = [&](size_t bytes) { char* p = ws + ofs; ofs += (bytes + 255) & ~(size_t)255; return p; };

    __hip_bfloat16* wn1_all  = (__hip_bfloat16*)alloc((size_t)3 * HIDF * HIDF * 2);  // 24 MB
    __hip_bfloat16* wn2b_all = (__hip_bfloat16*)alloc((size_t)3 * DIMN * HIDF * 2);
    float* wn0T_all = (float*)alloc((size_t)3 * DIMN * HIDF * 4);
    float* eg0_all  = (float*)alloc((size_t)3 * HIDF * 4);
    float* e1_all   = (float*)alloc((size_t)3 * HIDF * 32 * 4);
    float* e2_all   = (float*)alloc((size_t)3 * DIMN * 32 * 4);
    __hip_bfloat16* h0   = (__hip_bfloat16*)alloc((size_t)BATCH * HIDF * 2);
    __hip_bfloat16* part = (__hip_bfloat16*)alloc((size_t)SPLITK * BATCH * HIDF * 2); // 16 MB
    __hip_bfloat16* g0e    = (__hip_bfloat16*)alloc((size_t)BATCH * HIDF * 2);
    __hip_bfloat16* grad1e = (__hip_bfloat16*)alloc((size_t)BATCH * HIDF * 2);
    float* out2p  = (float*)alloc((size_t)NT2 * BATCH * DIMN * 4);                    // 8 MB
    float* x1     = (float*)alloc((size_t)BATCH * DIMN * 4);
    float* x2     = (float*)alloc((size_t)BATCH * DIMN * 4);
    float* ldj    = (float*)alloc(BATCH * 4);
    float* outp   = (float*)d_out;

    auto W = [&](int f, int i) { return (const float*)d_in[1 + f * 9 + i]; };

    PrepIn p0 = { W(0,0), W(0,1), W(0,3), W(0,4), W(0,6), W(0,7) };
    PrepIn p1 = { W(1,0), W(1,1), W(1,3), W(1,4), W(1,6), W(1,7) };
    PrepIn p2 = { W(2,0), W(2,1), W(2,3), W(2,4), W(2,6), W(2,7) };

    prep_mega<<<dim3(3 * 4160), dim3(64), 0, stream>>>(
        p0, p1, p2, wn0T_all, eg0_all, wn1_all, e1_all, wn2b_all, e2_all);

    gemm0_act<<<dim3(8, BATCH / 16), dim3(256), 0, stream>>>(
        x, wn0T_all, W(0,2), eg0_all, h0, g0e);

    const float* xcur = x;
    float* xnexts[2] = { x1, x2 };

    for (int f = 0; f < 3; ++f) {
        size_t fo1 = (size_t)f * HIDF * HIDF;
        size_t fo2 = (size_t)f * DIMN * HIDF;

        gemm1_part<<<dim3(320), dim3(256), 0, stream>>>(
            h0, wn1_all + fo1, part);

        act_grad_gemm2<<<dim3(HIDF / 64, BATCH / 64), dim3(256), 0, stream>>>(
            part, W(f,5), e1_all + (size_t)f * HIDF * 32, g0e,
            wn2b_all + fo2, grad1e, out2p);

        if (f < 2) {
            tail_trans<<<dim3(BATCH / 4), dim3(256), 0, stream>>>(
                out2p, W(f,8), e2_all + (size_t)f * DIMN * 32, grad1e,
                xcur, gates[f], xnexts[f], ldj, f);

            gemm0_act<<<dim3(8, BATCH / 16), dim3(256), 0, stream>>>(
                xnexts[f], wn0T_all + (size_t)(f + 1) * DIMN * HIDF, W(f + 1, 2),
                eg0_all + (size_t)(f + 1) * HIDF, h0, g0e);

            xcur = xnexts[f];
        } else {
            tail_final<<<dim3(BATCH / 4), dim3(256), 0, stream>>>(
                out2p, W(2,8), e2_all + (size_t)2 * DIMN * 32, grad1e, ldj, outp);
        }
    }
}